// Round 1
// baseline (374.118 us; speedup 1.0000x reference)
//
#include <hip/hip_runtime.h>

// Shapes fixed by the reference: N=2, C=32, H=W=64, O=32, K=3, stride=1, pad=1.
// out[n][o][oh][ow] = relu( sum_k patch[k] * filt[n, l, k, o] ),  l = oh*W+ow
// filters slice per (n,l): [288,32] row-major contiguous = 9216 floats (36 KB).
// filters = 302 MB read-once => memory-bound; kernel floor ~48 us at 6.3 TB/s.
//
// Measured config facts (prior rounds):
//  - nontemporal filter loads + __syncthreads = best; plain loads / no barrier
//    each regressed (+25 us). The 1.18 GB ws re-poison flushes L3 between the
//    filter restore and our kernel, so L3 never hits; nt streaming wins.
//  - occupancy-insensitive: 1 loc/wave @ 32 waves/CU vs 2 loc/wave @ 16
//    waves/CU differ by ~2 us -> MLP is not the limiter.
//
// THIS ROUND: fuse the pair's two 36 KB filter slices (contiguous in memory)
// into ONE sequential 72 KB stream per wave (two back-to-back sub-loops)
// instead of interleaving two streams 36 KB apart. Halves the concurrent
// DRAM stream count and removes the per-iteration 36 KB address ping-pong
// (row-locality theory, motivated by the measured barrier sensitivity).

#define C_   32
#define H_   64
#define W_   64
#define O_   32
#define CKK_ 288
#define L_   (H_ * W_)

typedef float vf4 __attribute__((ext_vector_type(4)));
typedef float vf2 __attribute__((ext_vector_type(2)));

__global__ __launch_bounds__(256) void convfilt_kernel(
    const float* __restrict__ features,
    const float* __restrict__ filters,
    float* __restrict__ out)
{
    const int wave = threadIdx.x >> 6;
    const int lane = threadIdx.x & 63;
    const int loc0 = blockIdx.x * 8 + wave * 2;   // even location; pair = loc0, loc0+1
    const int n    = loc0 >> 12;                  // / 4096
    const int l0   = loc0 & (L_ - 1);
    const int oh   = l0 >> 6;
    const int ow   = l0 & (W_ - 1);               // even => ow+1 stays in-row

    __shared__ float sf[4][2][CKK_];
    float* __restrict__ s0 = sf[wave][0];         // wave-private segments
    float* __restrict__ s1 = sf[wave][1];

    // ---- gather both 288-element feature patches (zero pad) into LDS ----
    #pragma unroll
    for (int q = 0; q < 5; ++q) {
        const int e = q * 64 + lane;              // q=4: only lanes <32 active
        if (e < CKK_) {
            const int c  = e / 9;
            const int r  = e % 9;
            const int ih = oh + (r / 3) - 1;
            const int iw = ow + (r % 3) - 1;
            float v0 = 0.0f, v1 = 0.0f;
            if ((unsigned)ih < (unsigned)H_) {
                const float* fb = features + ((n * C_ + c) * H_ + ih) * W_;
                if ((unsigned)iw       < (unsigned)W_) v0 = fb[iw];
                if ((unsigned)(iw + 1) < (unsigned)W_) v1 = fb[iw + 1];
            }
            s0[e] = v0;
            s1[e] = v1;
        }
    }
    __syncthreads();

    // ---- stream the pair's 72 KB as ONE sequential run: loc0 then loc1 ----
    const vf4* __restrict__ fp =
        (const vf4*)(filters + (size_t)loc0 * (CKK_ * O_));
    const int g = lane >> 3;                      // k-cluster: k = 8j + g

    float a0 = 0.f, a1 = 0.f, a2 = 0.f, a3 = 0.f;   // loc0 acc
    float b0 = 0.f, b1 = 0.f, b2 = 0.f, b3 = 0.f;   // loc1 acc

    #pragma unroll
    for (int j = 0; j < 36; ++j) {
        const vf4 f = __builtin_nontemporal_load(fp + j * 64 + lane);
        const float u = s0[j * 8 + g];
        a0 = fmaf(f.x, u, a0);  a1 = fmaf(f.y, u, a1);
        a2 = fmaf(f.z, u, a2);  a3 = fmaf(f.w, u, a3);
    }

    const vf4* __restrict__ fq = fp + 36 * 64;    // = next location's slice
    #pragma unroll
    for (int j = 0; j < 36; ++j) {
        const vf4 f = __builtin_nontemporal_load(fq + j * 64 + lane);
        const float u = s1[j * 8 + g];
        b0 = fmaf(f.x, u, b0);  b1 = fmaf(f.y, u, b1);
        b2 = fmaf(f.z, u, b2);  b3 = fmaf(f.w, u, b3);
    }

    // ---- reduce over the 8 clusters (lanes m, m+8, ..., m+56 share o-group) ----
    #pragma unroll
    for (int st = 8; st < 64; st <<= 1) {
        a0 += __shfl_down(a0, st);  a1 += __shfl_down(a1, st);
        a2 += __shfl_down(a2, st);  a3 += __shfl_down(a3, st);
        b0 += __shfl_down(b0, st);  b1 += __shfl_down(b1, st);
        b2 += __shfl_down(b2, st);  b3 += __shfl_down(b3, st);
    }

    // ---- ReLU + store: lane m (<8) owns o = 4m..4m+3; l0,l0+1 contiguous ----
    if (lane < 8) {
        float* op = out + ((size_t)n * O_ + lane * 4) * L_ + l0;
        vf2 r0 = { fmaxf(a0, 0.f), fmaxf(b0, 0.f) };
        vf2 r1 = { fmaxf(a1, 0.f), fmaxf(b1, 0.f) };
        vf2 r2 = { fmaxf(a2, 0.f), fmaxf(b2, 0.f) };
        vf2 r3 = { fmaxf(a3, 0.f), fmaxf(b3, 0.f) };
        *(vf2*)(op + 0 * L_) = r0;
        *(vf2*)(op + 1 * L_) = r1;
        *(vf2*)(op + 2 * L_) = r2;
        *(vf2*)(op + 3 * L_) = r3;
    }
}

extern "C" void kernel_launch(void* const* d_in, const int* in_sizes, int n_in,
                              void* d_out, int out_size, void* d_ws, size_t ws_size,
                              hipStream_t stream)
{
    const float* features = (const float*)d_in[0];   // [N, C, H, W]
    const float* filters  = (const float*)d_in[1];   // [N, L, Ckk, O]
    float* out            = (float*)d_out;           // [N, O, H, W]

    const int N     = in_sizes[0] / (C_ * H_ * W_);  // = 2
    const int total = N * L_;                        // 8192 locations
    const int grid  = total / 8;                     // 4 waves x 2 locations per block

    convfilt_kernel<<<grid, 256, 0, stream>>>(features, filters, out);
}